// Round 7
// baseline (299.873 us; speedup 1.0000x reference)
//
#include <hip/hip_runtime.h>

#define NB  4
#define CKQ 384
#define DH  128
#define HH  48
#define WW  64
#define HW  3072

#define NSPLIT 8
#define KSEG  (HW / NSPLIT)   // 384 keys per block
#define BQ 128                // queries per block (32 per wave, 4 waves)
#define BK 32                 // keys per tile
#define NIT (KSEG / BK)       // 12 tiles per block
#define VSP 40                // Vs row stride (bytes)
#define PTS 40                // Pt row stride (bytes)

typedef short bf16x8 __attribute__((ext_vector_type(8)));
typedef short b16x4  __attribute__((ext_vector_type(4)));
typedef float f32x4  __attribute__((ext_vector_type(4)));
typedef long  i64;
typedef long  i64x2 __attribute__((ext_vector_type(2)));
typedef unsigned short u16;
typedef unsigned int   u32;
typedef unsigned char  u8;
typedef unsigned long long u64;

__device__ __forceinline__ float b2f(u16 u){
  union { u32 i; float f; } x; x.i = ((u32)u) << 16; return x.f;
}
__device__ __forceinline__ u16 f2b(float f){
  union { float f; u32 i; } x; x.f = f;
  u32 r = (x.i + 0x7fffu + ((x.i >> 16) & 1u)) >> 16;
  return (u16)r;
}
__device__ __forceinline__ u8 f2f8(float f){
  return (u8)(__builtin_amdgcn_cvt_pk_fp8_f32(f, f, 0, false) & 0xff);
}

// ---------------------------------------------------------------------------
// Kernel T8: K,Q fp32 [n][c][p] -> fp8 e4m3 [n][p][c].
// One block: 64-p strip x full 384 c -> writes are long contiguous runs.
// grid (48, 8): y<4 -> K (n=y), else Q. block 256
// ---------------------------------------------------------------------------
__global__ __launch_bounds__(256)
void tcast8(const float* __restrict__ kin, const float* __restrict__ qin,
            u8* __restrict__ kt8, u8* __restrict__ qt8){
  __shared__ u8 T[64][392];    // [p][c], row stride 392 (8B-aligned)
  const int yy = blockIdx.y;
  const float* in = (yy < NB) ? kin : qin;
  u8* out         = (yy < NB) ? kt8 : qt8;
  const int n  = yy & (NB - 1);
  const int p0 = blockIdx.x * 64;
  const int tx = threadIdx.x & 63;   // p
  const int ty = threadIdx.x >> 6;   // 0..3
  const float* ib = in + (size_t)n * CKQ * HW + p0;
  #pragma unroll 4
  for (int c = ty; c < CKQ; c += 4)
    T[tx][c] = f2f8(ib[(size_t)c * HW + tx]);
  __syncthreads();
  u8* ob = out + ((size_t)n * HW + p0) * CKQ;
  // 3072 8B-chunks, contiguous within each 384B row
  #pragma unroll
  for (int it = 0; it < 12; ++it){
    int ch  = it * 256 + threadIdx.x;
    int row = ch / 48;
    int g   = ch - row * 48;
    *(u64*)(ob + (size_t)row * CKQ + g * 8) = *(const u64*)&T[row][g * 8];
  }
}

// ---------------------------------------------------------------------------
// Kernel W: all three conv weights fp32 OIHW -> bf16 [tap][d][c]
// grid (64, 3) block 256
// ---------------------------------------------------------------------------
__global__ __launch_bounds__(256)
void wprep3(const float* __restrict__ w0, const float* __restrict__ w1,
            const float* __restrict__ w2, u16* __restrict__ o0,
            u16* __restrict__ o1, u16* __restrict__ o2){
  const float* w = (blockIdx.y == 0) ? w0 : (blockIdx.y == 1) ? w1 : w2;
  u16* wt        = (blockIdx.y == 0) ? o0 : (blockIdx.y == 1) ? o1 : o2;
  int idx = blockIdx.x * 256 + threadIdx.x;   // d*128 + c
  int d = idx >> 7, c = idx & 127;
  #pragma unroll
  for (int tap = 0; tap < 9; ++tap)
    wt[((size_t)tap * DH + d) * DH + c] = f2b(w[(size_t)idx * 9 + tap]);
}

// ---------------------------------------------------------------------------
// Kernel A: val = w_value(128x128) @ v  (1x1 conv). fp32 in -> fp8 [d][p].
// grid (12, 32, 4) block 256
// ---------------------------------------------------------------------------
__global__ __launch_bounds__(256)
void val_embed8(const float* __restrict__ v, const float* __restrict__ wv,
                u8* __restrict__ val8){
  int p  = blockIdx.x * 256 + threadIdx.x;
  int d0 = blockIdx.y * 4;
  int n  = blockIdx.z;
  const float* vb = v + (size_t)n * DH * HW;
  float a0 = 0.f, a1 = 0.f, a2 = 0.f, a3 = 0.f;
  for (int c = 0; c < DH; ++c){
    float vv = vb[c * HW + p];
    a0 += wv[(d0 + 0) * DH + c] * vv;
    a1 += wv[(d0 + 1) * DH + c] * vv;
    a2 += wv[(d0 + 2) * DH + c] * vv;
    a3 += wv[(d0 + 3) * DH + c] * vv;
  }
  u8* ob = val8 + (size_t)n * DH * HW;
  ob[(d0 + 0) * HW + p] = f2f8(a0);
  ob[(d0 + 1) * HW + p] = f2f8(a1);
  ob[(d0 + 2) * HW + p] = f2f8(a2);
  ob[(d0 + 3) * HW + p] = f2f8(a3);
}

// ---------------------------------------------------------------------------
// Kernel B: split-K flash attention, fp8 operands, register-prefetch pipeline:
// next K/V tile's global loads are issued right after the stage-barrier and
// land in VGPRs while the current tile's MFMAs run (cp.async-style overlap).
// grid (24, NSPLIT, 4) block 256, launch_bounds(256,3) -> 3 blocks/CU
// ---------------------------------------------------------------------------
__global__ __launch_bounds__(256, 3)
void attn8(const u8* __restrict__ kt, const u8* __restrict__ qt,
           const u8* __restrict__ val, u16* __restrict__ outp,
           float* __restrict__ lsum){
  __shared__ u8 Ks[BK * CKQ];     // 12 KB
  __shared__ u8 Vs[DH * VSP];     // 5 KB
  __shared__ u8 Pt[BQ * PTS];     // 5 KB

  const int tid  = threadIdx.x;
  const int wv   = tid >> 6;
  const int lane = tid & 63;
  const int quad = lane >> 4;
  const int l15  = lane & 15;
  const int n    = blockIdx.z;
  const int seg  = blockIdx.y;
  const int j0   = blockIdx.x * BQ;
  const int jra  = wv * 32 + l15;
  const int jrb  = jra + 16;
  const int ja   = j0 + jra;
  const int jb   = j0 + jrb;

  const u8* ktb = kt  + (size_t)n * CKQ * HW;
  const u8* vb  = val + (size_t)n * DH * HW;

  // per-thread staging slices: K 3x16B, V 2x8B
  const int ki[3] = { tid, tid + 256, tid + 512 };        // of BK*24 16B-chunks
  const int vi0 = tid, vi1 = tid + 256;                   // of DH*4 8B-chunks

  // Q fragments, both j-sets: 24 x i64 = 48 VGPR
  const u8* qrowa = qt + ((size_t)n * HW + ja) * CKQ;
  const u8* qrowb = qt + ((size_t)n * HW + jb) * CKQ;
  i64 qfa[12], qfb[12];
  #pragma unroll
  for (int cs = 0; cs < 12; ++cs){
    qfa[cs] = *(const i64*)&qrowa[cs * 32 + quad * 8];
    qfb[cs] = *(const i64*)&qrowb[cs * 32 + quad * 8];
  }

  const f32x4 zero = {0.f, 0.f, 0.f, 0.f};
  f32x4 oa[8], obacc[8];
  #pragma unroll
  for (int i = 0; i < 8; ++i){ oa[i] = zero; obacc[i] = zero; }
  float la = 0.f, lbv = 0.f;

  const float scale = 0.05103103630798287f;  // 1/sqrt(384)

  // prefetch tile 0
  i64x2 kr[3]; i64 vr[2];
  {
    const int i0 = seg * KSEG;
    #pragma unroll
    for (int r = 0; r < 3; ++r){
      int i = ki[r] / 24, g2 = ki[r] % 24;
      kr[r] = *(const i64x2*)&ktb[(size_t)(i0 + i) * CKQ + g2 * 16];
    }
    vr[0] = *(const i64*)&vb[(size_t)(vi0 >> 2) * HW + i0 + (vi0 & 3) * 8];
    vr[1] = *(const i64*)&vb[(size_t)(vi1 >> 2) * HW + i0 + (vi1 & 3) * 8];
  }

  for (int it = 0; it < NIT; ++it){
    // write prefetched regs -> LDS (XOR-swizzled K)
    #pragma unroll
    for (int r = 0; r < 3; ++r){
      int i = ki[r] / 24, g2 = ki[r] % 24;
      int g0 = 2 * g2, g1 = g0 + 1;
      int gs0 = (g0 & ~7) | ((g0 ^ i) & 7);
      int gs1 = (g1 & ~7) | ((g1 ^ i) & 7);
      *(i64*)&Ks[i * CKQ + gs0 * 8] = kr[r][0];
      *(i64*)&Ks[i * CKQ + gs1 * 8] = kr[r][1];
    }
    *(i64*)&Vs[(vi0 >> 2) * VSP + (vi0 & 3) * 8] = vr[0];
    *(i64*)&Vs[(vi1 >> 2) * VSP + (vi1 & 3) * 8] = vr[1];
    __syncthreads();

    // issue next tile's global loads now; they complete during the MFMAs
    if (it + 1 < NIT){
      const int i0n = seg * KSEG + (it + 1) * BK;
      #pragma unroll
      for (int r = 0; r < 3; ++r){
        int i = ki[r] / 24, g2 = ki[r] % 24;
        kr[r] = *(const i64x2*)&ktb[(size_t)(i0n + i) * CKQ + g2 * 16];
      }
      vr[0] = *(const i64*)&vb[(size_t)(vi0 >> 2) * HW + i0n + (vi0 & 3) * 8];
      vr[1] = *(const i64*)&vb[(size_t)(vi1 >> 2) * HW + i0n + (vi1 & 3) * 8];
    }

    // S = K^T Q  (2 key-subtiles x 12 c-steps; a0/a1 shared by both j-sets)
    f32x4 s0a = zero, s1a = zero, s0b = zero, s1b = zero;
    #pragma unroll
    for (int cs = 0; cs < 12; ++cs){
      int g  = 4 * cs + quad;
      int gs = (g & ~7) | ((g ^ l15) & 7);   // rows r and 16+r share low3
      i64 a0 = *(const i64*)&Ks[l15 * CKQ + gs * 8];
      i64 a1 = *(const i64*)&Ks[(16 + l15) * CKQ + gs * 8];
      s0a = __builtin_amdgcn_mfma_f32_16x16x32_fp8_fp8(a0, qfa[cs], s0a, 0, 0, 0);
      s1a = __builtin_amdgcn_mfma_f32_16x16x32_fp8_fp8(a1, qfa[cs], s1a, 0, 0, 0);
      s0b = __builtin_amdgcn_mfma_f32_16x16x32_fp8_fp8(a0, qfb[cs], s0b, 0, 0, 0);
      s1b = __builtin_amdgcn_mfma_f32_16x16x32_fp8_fp8(a1, qfb[cs], s1b, 0, 0, 0);
    }

    // p = exp(s*scale)
    float pa[8], pb[8]; float tsa = 0.f, tsb = 0.f;
    #pragma unroll
    for (int r = 0; r < 4; ++r){
      pa[r]     = __expf(s0a[r] * scale);
      pa[4 + r] = __expf(s1a[r] * scale);
      pb[r]     = __expf(s0b[r] * scale);
      pb[4 + r] = __expf(s1b[r] * scale);
    }
    #pragma unroll
    for (int i = 0; i < 8; ++i){ tsa += pa[i]; tsb += pb[i]; }
    la += tsa; lbv += tsb;

    // P -> LDS as fp8, transposed (Pt[j][i])
    u32 wa0 = __builtin_amdgcn_cvt_pk_fp8_f32(pa[0], pa[1], 0, false);
    wa0     = __builtin_amdgcn_cvt_pk_fp8_f32(pa[2], pa[3], wa0, true);
    u32 wa1 = __builtin_amdgcn_cvt_pk_fp8_f32(pa[4], pa[5], 0, false);
    wa1     = __builtin_amdgcn_cvt_pk_fp8_f32(pa[6], pa[7], wa1, true);
    u32 wb0 = __builtin_amdgcn_cvt_pk_fp8_f32(pb[0], pb[1], 0, false);
    wb0     = __builtin_amdgcn_cvt_pk_fp8_f32(pb[2], pb[3], wb0, true);
    u32 wb1 = __builtin_amdgcn_cvt_pk_fp8_f32(pb[4], pb[5], 0, false);
    wb1     = __builtin_amdgcn_cvt_pk_fp8_f32(pb[6], pb[7], wb1, true);
    *(u32*)&Pt[jra * PTS + quad * 4]      = wa0;
    *(u32*)&Pt[jra * PTS + 16 + quad * 4] = wa1;
    *(u32*)&Pt[jrb * PTS + quad * 4]      = wb0;
    *(u32*)&Pt[jrb * PTS + 16 + quad * 4] = wb1;
    __builtin_amdgcn_wave_barrier();   // rows are wave-private; pin order

    // O += V * P
    i64 bpa = *(const i64*)&Pt[jra * PTS + quad * 8];
    i64 bpb = *(const i64*)&Pt[jrb * PTS + quad * 8];
    #pragma unroll
    for (int dt = 0; dt < 8; ++dt){
      i64 av = *(const i64*)&Vs[(dt * 16 + l15) * VSP + quad * 8];
      oa[dt]    = __builtin_amdgcn_mfma_f32_16x16x32_fp8_fp8(av, bpa, oa[dt], 0, 0, 0);
      obacc[dt] = __builtin_amdgcn_mfma_f32_16x16x32_fp8_fp8(av, bpb, obacc[dt], 0, 0, 0);
    }
    __syncthreads();   // all waves done with Ks/Vs before next write
  }

  la  += __shfl_xor(la, 16);  la  += __shfl_xor(la, 32);
  lbv += __shfl_xor(lbv, 16); lbv += __shfl_xor(lbv, 32);

  // partials: outp[(seg*NB+n)][j][d] bf16 (8B packed per lane), l fp32
  u16* obp = outp + ((size_t)(seg * NB + n) * HW) * DH;
  #pragma unroll
  for (int dt = 0; dt < 8; ++dt){
    b16x4 pka = { (short)f2b(oa[dt][0]), (short)f2b(oa[dt][1]),
                  (short)f2b(oa[dt][2]), (short)f2b(oa[dt][3]) };
    b16x4 pkb = { (short)f2b(obacc[dt][0]), (short)f2b(obacc[dt][1]),
                  (short)f2b(obacc[dt][2]), (short)f2b(obacc[dt][3]) };
    *(b16x4*)&obp[(size_t)ja * DH + dt * 16 + quad * 4] = pka;
    *(b16x4*)&obp[(size_t)jb * DH + dt * 16 + quad * 4] = pkb;
  }
  if (quad == 0){
    lsum[(size_t)(seg * NB + n) * HW + ja] = la;
    lsum[(size_t)(seg * NB + n) * HW + jb] = lbv;
  }
}

// ---------------------------------------------------------------------------
// Kernel B2: pval_t[n][j][d] = (sum_s o_s) / (sum_s l_s)  -- fully coalesced
// ---------------------------------------------------------------------------
__global__ __launch_bounds__(256)
void combine(const u16* __restrict__ ob, const float* __restrict__ lb,
             u16* __restrict__ pval_t){
  size_t flat = (size_t)blockIdx.x * 256 + threadIdx.x;
  int d = (int)(flat & 127);
  size_t nj = flat >> 7;
  int j = (int)(nj % HW);
  int n = (int)(nj / HW);
  float acc = 0.f, ls = 0.f;
  #pragma unroll
  for (int s = 0; s < NSPLIT; ++s){
    acc += b2f(ob[((size_t)(s * NB + n) * HW + j) * DH + d]);
    ls  += lb[(size_t)(s * NB + n) * HW + j];
  }
  pval_t[flat] = f2b(acc / ls);
}

// ---------------------------------------------------------------------------
// Kernel C: MFMA implicit-GEMM 3x3 conv + LeakyReLU [+ residual].
// Input bf16 [n][p][c]; weights bf16 [tap][d][c]; no LDS, no barriers.
// RESM: 0 none, 1 fp32 [c][p], 2 bf16 [p][c].  OUTM: 0 bf16 [p][c], 1 fp32 [c][p].
// ---------------------------------------------------------------------------
template<int DIL, int RESM, int OUTM>
__global__ __launch_bounds__(256, 3)
void mconv(const u16* __restrict__ in_t, const u16* __restrict__ wt,
           const void* __restrict__ res, void* __restrict__ out){
  const int tid  = threadIdx.x;
  const int w    = tid >> 6;
  const int lane = tid & 63;
  const int quad = lane >> 4;
  const int l15  = lane & 15;
  const int n    = blockIdx.z;
  const int p0   = blockIdx.x * 32;
  const int d0   = (blockIdx.y * 4 + w) * 16;
  const int y    = p0 >> 6;          // wave-uniform row
  const int x0   = p0 & 63;

  const u16* ib = in_t + (size_t)n * HW * DH;
  f32x4 acc0 = {0.f, 0.f, 0.f, 0.f};
  f32x4 acc1 = {0.f, 0.f, 0.f, 0.f};
  const bf16x8 bzero = {0, 0, 0, 0, 0, 0, 0, 0};

  #pragma unroll
  for (int tap = 0; tap < 9; ++tap){
    const int dy = (tap / 3 - 1) * DIL;
    const int dx = (tap % 3 - 1) * DIL;
    if ((unsigned)(y + dy) >= (unsigned)HH) continue;   // uniform skip
    const int off = dy * WW + dx;
    const bool vx0 = (unsigned)(x0 + l15 + dx)      < (unsigned)WW;
    const bool vx1 = (unsigned)(x0 + 16 + l15 + dx) < (unsigned)WW;
    const u16* brow0 = ib + (size_t)(p0 + l15 + off) * DH;
    const u16* brow1 = brow0 + (size_t)16 * DH;
    const u16* wrow  = wt + ((size_t)tap * DH + d0 + l15) * DH;
    #pragma unroll
    for (int c0 = 0; c0 < DH; c0 += 32){
      bf16x8 af = *(const bf16x8*)&wrow[c0 + quad * 8];
      bf16x8 b0 = bzero, b1 = bzero;
      if (vx0) b0 = *(const bf16x8*)&brow0[c0 + quad * 8];
      if (vx1) b1 = *(const bf16x8*)&brow1[c0 + quad * 8];
      acc0 = __builtin_amdgcn_mfma_f32_16x16x32_bf16(af, b0, acc0, 0, 0, 0);
      acc1 = __builtin_amdgcn_mfma_f32_16x16x32_bf16(af, b1, acc1, 0, 0, 0);
    }
  }

  #pragma unroll
  for (int pt = 0; pt < 2; ++pt){
    f32x4 a = pt ? acc1 : acc0;
    const int p = p0 + pt * 16 + l15;
    float v4[4];
    #pragma unroll
    for (int r = 0; r < 4; ++r){
      float vv = a[r];
      vv = (vv >= 0.f) ? vv : 0.2f * vv;
      if (RESM == 1)
        vv += ((const float*)res)[((size_t)n * DH + d0 + quad * 4 + r) * HW + p];
      v4[r] = vv;
    }
    if (RESM == 2){
      b16x4 rv = *(const b16x4*)&((const u16*)res)[((size_t)n * HW + p) * DH + d0 + quad * 4];
      #pragma unroll
      for (int r = 0; r < 4; ++r) v4[r] += b2f((u16)rv[r]);
    }
    if (OUTM == 0){
      b16x4 pk = { (short)f2b(v4[0]), (short)f2b(v4[1]),
                   (short)f2b(v4[2]), (short)f2b(v4[3]) };
      *(b16x4*)&((u16*)out)[((size_t)n * HW + p) * DH + d0 + quad * 4] = pk;
    } else {
      #pragma unroll
      for (int r = 0; r < 4; ++r)
        ((float*)out)[((size_t)n * DH + d0 + quad * 4 + r) * HW + p] = v4[r];
    }
  }
}

// ---------------------------------------------------------------------------
extern "C" void kernel_launch(void* const* d_in, const int* in_sizes, int n_in,
                              void* d_out, int out_size, void* d_ws, size_t ws_size,
                              hipStream_t stream){
  const float* k    = (const float*)d_in[0];
  const float* q    = (const float*)d_in[1];
  const float* v    = (const float*)d_in[2];
  const float* wv   = (const float*)d_in[3];
  const float* wout = (const float*)d_in[4];
  const float* wff1 = (const float*)d_in[5];
  const float* wff2 = (const float*)d_in[6];
  float* out = (float*)d_out;

  const size_t TEN  = (size_t)NB * DH * HW;    // 1,572,864
  const size_t KTEN = (size_t)NB * CKQ * HW;   // 4,718,592
  const size_t WT   = (size_t)9 * DH * DH;     // 147,456
  u8*  kt8    = (u8*)d_ws;                     // KTEN bytes
  u8*  qt8    = kt8 + KTEN;                    // KTEN bytes
  u8*  val8   = qt8 + KTEN;                    // TEN bytes
  u16* wt1    = (u16*)(val8 + TEN);
  u16* wt2    = wt1 + WT;
  u16* wt3    = wt2 + WT;
  u16* pval_t = wt3 + WT;
  u16* v2_t   = pval_t + TEN;
  u16* tmid_t = v2_t + TEN;
  u16* ob     = tmid_t + TEN;                  // NSPLIT*TEN bf16
  float* lb   = (float*)(ob + (size_t)NSPLIT * TEN);

  tcast8    <<<dim3(48, 2 * NB), 256, 0, stream>>>(k, q, kt8, qt8);
  wprep3    <<<dim3(64, 3), 256, 0, stream>>>(wout, wff1, wff2, wt1, wt2, wt3);
  val_embed8<<<dim3(12, 32, NB), 256, 0, stream>>>(v, wv, val8);
  attn8     <<<dim3(HW / BQ, NSPLIT, NB), 256, 0, stream>>>(kt8, qt8, val8, ob, lb);
  combine   <<<dim3((unsigned)(TEN / 256)), 256, 0, stream>>>(ob, lb, pval_t);
  mconv<1, 1, 0><<<dim3(96, 2, NB), 256, 0, stream>>>(pval_t, wt1, (const void*)v,    (void*)v2_t);
  mconv<2, 0, 0><<<dim3(96, 2, NB), 256, 0, stream>>>(v2_t,   wt2, (const void*)nullptr, (void*)tmid_t);
  mconv<1, 2, 1><<<dim3(96, 2, NB), 256, 0, stream>>>(tmid_t, wt3, (const void*)v2_t, (void*)out);
}

// Round 8
// 231.862 us; speedup vs baseline: 1.2933x; 1.2933x over previous
//
#include <hip/hip_runtime.h>

#define NB  4
#define CKQ 384
#define DH  128
#define HH  48
#define WW  64
#define HW  3072

#define NSPLIT 16
#define KSEG  (HW / NSPLIT)   // 192 keys per block
#define BQ 128                // queries per block (32 per wave, 4 waves)
#define BK 32                 // keys per tile
#define VSP 40                // Vs row stride (bytes)
#define PTS 40                // Pt row stride (bytes)
#define XROW 136              // mconv staged row stride in u16 (272B: 2-way free)

typedef short bf16x8 __attribute__((ext_vector_type(8)));
typedef short b16x4  __attribute__((ext_vector_type(4)));
typedef float f32x4  __attribute__((ext_vector_type(4)));
typedef long  i64;
typedef long  i64x2 __attribute__((ext_vector_type(2)));
typedef unsigned short u16;
typedef unsigned int   u32;
typedef unsigned char  u8;
typedef unsigned long long u64;

__device__ __forceinline__ float b2f(u16 u){
  union { u32 i; float f; } x; x.i = ((u32)u) << 16; return x.f;
}
__device__ __forceinline__ u16 f2b(float f){
  union { float f; u32 i; } x; x.f = f;
  u32 r = (x.i + 0x7fffu + ((x.i >> 16) & 1u)) >> 16;
  return (u16)r;
}
__device__ __forceinline__ u8 f2f8(float f){
  return (u8)(__builtin_amdgcn_cvt_pk_fp8_f32(f, f, 0, false) & 0xff);
}

// ---------------------------------------------------------------------------
// Kernel T8: K,Q fp32 [n][c][p] -> fp8 e4m3 [n][p][c].
// One block: 64-p strip x full 384 c -> contiguous output runs.
// grid (48, 8): y<4 -> K (n=y), else Q. block 256
// ---------------------------------------------------------------------------
__global__ __launch_bounds__(256)
void tcast8(const float* __restrict__ kin, const float* __restrict__ qin,
            u8* __restrict__ kt8, u8* __restrict__ qt8){
  __shared__ u8 T[64][392];
  const int yy = blockIdx.y;
  const float* in = (yy < NB) ? kin : qin;
  u8* out         = (yy < NB) ? kt8 : qt8;
  const int n  = yy & (NB - 1);
  const int p0 = blockIdx.x * 64;
  const int tx = threadIdx.x & 63;
  const int ty = threadIdx.x >> 6;
  const float* ib = in + (size_t)n * CKQ * HW + p0;
  #pragma unroll 4
  for (int c = ty; c < CKQ; c += 4)
    T[tx][c] = f2f8(ib[(size_t)c * HW + tx]);
  __syncthreads();
  u8* ob = out + ((size_t)n * HW + p0) * CKQ;
  #pragma unroll
  for (int it = 0; it < 12; ++it){
    int ch  = it * 256 + threadIdx.x;
    int row = ch / 48;
    int g   = ch - row * 48;
    *(u64*)(ob + (size_t)row * CKQ + g * 8) = *(const u64*)&T[row][g * 8];
  }
}

// ---------------------------------------------------------------------------
// Kernel W: conv weights fp32 OIHW -> bf16 A-fragment stream layout:
//   frag id f = (tap*4 + cst)*8 + dtile;  frag = 64 lanes x 8 elems (1KB)
//   lane = quad*16 + l15 holds w[d = dtile*16+l15][c = cst*32+quad*8+e][tap]
// grid (72, 3) block 256
// ---------------------------------------------------------------------------
__global__ __launch_bounds__(256)
void wprep3(const float* __restrict__ w0, const float* __restrict__ w1,
            const float* __restrict__ w2, u16* __restrict__ o0,
            u16* __restrict__ o1, u16* __restrict__ o2){
  const float* w = (blockIdx.y == 0) ? w0 : (blockIdx.y == 1) ? w1 : w2;
  u16* wt        = (blockIdx.y == 0) ? o0 : (blockIdx.y == 1) ? o1 : o2;
  int g    = blockIdx.x * 256 + threadIdx.x;   // frag*64 + lane
  int fid  = g >> 6;
  int lane = g & 63;
  int l15  = lane & 15, quad = lane >> 4;
  int tap  = fid >> 5;
  int cst  = (fid >> 3) & 3;
  int dt   = fid & 7;
  int d    = dt * 16 + l15;
  u16* dst = wt + (size_t)fid * 512 + lane * 8;
  #pragma unroll
  for (int e = 0; e < 8; ++e){
    int c = cst * 32 + quad * 8 + e;
    dst[e] = f2b(w[((size_t)d * DH + c) * 9 + tap]);
  }
}

// ---------------------------------------------------------------------------
// Kernel A: val = w_value(128x128) @ v  (1x1 conv). fp32 in -> fp8 [d][p].
// grid (12, 32, 4) block 256
// ---------------------------------------------------------------------------
__global__ __launch_bounds__(256)
void val_embed8(const float* __restrict__ v, const float* __restrict__ wv,
                u8* __restrict__ val8){
  int p  = blockIdx.x * 256 + threadIdx.x;
  int d0 = blockIdx.y * 4;
  int n  = blockIdx.z;
  const float* vb = v + (size_t)n * DH * HW;
  float a0 = 0.f, a1 = 0.f, a2 = 0.f, a3 = 0.f;
  for (int c = 0; c < DH; ++c){
    float vv = vb[c * HW + p];
    a0 += wv[(d0 + 0) * DH + c] * vv;
    a1 += wv[(d0 + 1) * DH + c] * vv;
    a2 += wv[(d0 + 2) * DH + c] * vv;
    a3 += wv[(d0 + 3) * DH + c] * vv;
  }
  u8* ob = val8 + (size_t)n * DH * HW;
  ob[(d0 + 0) * HW + p] = f2f8(a0);
  ob[(d0 + 1) * HW + p] = f2f8(a1);
  ob[(d0 + 2) * HW + p] = f2f8(a2);
  ob[(d0 + 3) * HW + p] = f2f8(a3);
}

// ---------------------------------------------------------------------------
// Kernel B: split-K flash attention, fp8 operands (R6-proven version).
// grid (24, NSPLIT, 4) block 256, launch_bounds(256,3) -> 3 blocks/CU
// ---------------------------------------------------------------------------
__global__ __launch_bounds__(256, 3)
void attn8(const u8* __restrict__ kt, const u8* __restrict__ qt,
           const u8* __restrict__ val, u16* __restrict__ outp,
           float* __restrict__ lsum){
  __shared__ u8 Ks[BK * CKQ];     // 12 KB
  __shared__ u8 Vs[DH * VSP];     // 5 KB
  __shared__ u8 Pt[BQ * PTS];     // 5 KB

  const int tid  = threadIdx.x;
  const int wv   = tid >> 6;
  const int lane = tid & 63;
  const int quad = lane >> 4;
  const int l15  = lane & 15;
  const int n    = blockIdx.z;
  const int seg  = blockIdx.y;
  const int j0   = blockIdx.x * BQ;
  const int jra  = wv * 32 + l15;
  const int jrb  = jra + 16;
  const int ja   = j0 + jra;
  const int jb   = j0 + jrb;

  const u8* qrowa = qt + ((size_t)n * HW + ja) * CKQ;
  const u8* qrowb = qt + ((size_t)n * HW + jb) * CKQ;
  i64 qfa[12], qfb[12];
  #pragma unroll
  for (int cs = 0; cs < 12; ++cs){
    qfa[cs] = *(const i64*)&qrowa[cs * 32 + quad * 8];
    qfb[cs] = *(const i64*)&qrowb[cs * 32 + quad * 8];
  }

  const f32x4 zero = {0.f, 0.f, 0.f, 0.f};
  f32x4 oa[8], obacc[8];
  #pragma unroll
  for (int i = 0; i < 8; ++i){ oa[i] = zero; obacc[i] = zero; }
  float la = 0.f, lbv = 0.f;

  const u8* ktb = kt  + (size_t)n * CKQ * HW;
  const u8* vb  = val + (size_t)n * DH * HW;
  const float scale = 0.05103103630798287f;  // 1/sqrt(384)

  for (int it = 0; it < KSEG / BK; ++it){
    const int i0 = seg * KSEG + it * BK;
    // stage K: 16B global loads -> two swizzled 8B LDS writes
    for (int idx = tid; idx < BK * 24; idx += 256){
      int i  = idx / 24;
      int g2 = idx % 24;
      i64x2 dv = *(const i64x2*)&ktb[(size_t)(i0 + i) * CKQ + g2 * 16];
      int g0 = 2 * g2, g1 = g0 + 1;
      int gs0 = (g0 & ~7) | ((g0 ^ i) & 7);
      int gs1 = (g1 & ~7) | ((g1 ^ i) & 7);
      *(i64*)&Ks[i * CKQ + gs0 * 8] = dv[0];
      *(i64*)&Ks[i * CKQ + gs1 * 8] = dv[1];
    }
    // stage V: 8B chunks, row stride VSP
    for (int idx = tid; idx < DH * 4; idx += 256){
      int dd = idx >> 2;
      int c8 = idx & 3;
      *(i64*)&Vs[dd * VSP + c8 * 8] = *(const i64*)&vb[(size_t)dd * HW + i0 + c8 * 8];
    }
    __syncthreads();

    // S = K^T Q  (2 key-subtiles x 12 c-steps; a0/a1 shared by both j-sets)
    f32x4 s0a = zero, s1a = zero, s0b = zero, s1b = zero;
    #pragma unroll
    for (int cs = 0; cs < 12; ++cs){
      int g  = 4 * cs + quad;
      int gs = (g & ~7) | ((g ^ l15) & 7);
      i64 a0 = *(const i64*)&Ks[l15 * CKQ + gs * 8];
      i64 a1 = *(const i64*)&Ks[(16 + l15) * CKQ + gs * 8];
      s0a = __builtin_amdgcn_mfma_f32_16x16x32_fp8_fp8(a0, qfa[cs], s0a, 0, 0, 0);
      s1a = __builtin_amdgcn_mfma_f32_16x16x32_fp8_fp8(a1, qfa[cs], s1a, 0, 0, 0);
      s0b = __builtin_amdgcn_mfma_f32_16x16x32_fp8_fp8(a0, qfb[cs], s0b, 0, 0, 0);
      s1b = __builtin_amdgcn_mfma_f32_16x16x32_fp8_fp8(a1, qfb[cs], s1b, 0, 0, 0);
    }

    float pa[8], pb[8]; float tsa = 0.f, tsb = 0.f;
    #pragma unroll
    for (int r = 0; r < 4; ++r){
      pa[r]     = __expf(s0a[r] * scale);
      pa[4 + r] = __expf(s1a[r] * scale);
      pb[r]     = __expf(s0b[r] * scale);
      pb[4 + r] = __expf(s1b[r] * scale);
    }
    #pragma unroll
    for (int i = 0; i < 8; ++i){ tsa += pa[i]; tsb += pb[i]; }
    la += tsa; lbv += tsb;

    u32 wa0 = __builtin_amdgcn_cvt_pk_fp8_f32(pa[0], pa[1], 0, false);
    wa0     = __builtin_amdgcn_cvt_pk_fp8_f32(pa[2], pa[3], wa0, true);
    u32 wa1 = __builtin_amdgcn_cvt_pk_fp8_f32(pa[4], pa[5], 0, false);
    wa1     = __builtin_amdgcn_cvt_pk_fp8_f32(pa[6], pa[7], wa1, true);
    u32 wb0 = __builtin_amdgcn_cvt_pk_fp8_f32(pb[0], pb[1], 0, false);
    wb0     = __builtin_amdgcn_cvt_pk_fp8_f32(pb[2], pb[3], wb0, true);
    u32 wb1 = __builtin_amdgcn_cvt_pk_fp8_f32(pb[4], pb[5], 0, false);
    wb1     = __builtin_amdgcn_cvt_pk_fp8_f32(pb[6], pb[7], wb1, true);
    *(u32*)&Pt[jra * PTS + quad * 4]      = wa0;
    *(u32*)&Pt[jra * PTS + 16 + quad * 4] = wa1;
    *(u32*)&Pt[jrb * PTS + quad * 4]      = wb0;
    *(u32*)&Pt[jrb * PTS + 16 + quad * 4] = wb1;
    __builtin_amdgcn_wave_barrier();

    i64 bpa = *(const i64*)&Pt[jra * PTS + quad * 8];
    i64 bpb = *(const i64*)&Pt[jrb * PTS + quad * 8];
    #pragma unroll
    for (int dt = 0; dt < 8; ++dt){
      i64 av = *(const i64*)&Vs[(dt * 16 + l15) * VSP + quad * 8];
      oa[dt]    = __builtin_amdgcn_mfma_f32_16x16x32_fp8_fp8(av, bpa, oa[dt], 0, 0, 0);
      obacc[dt] = __builtin_amdgcn_mfma_f32_16x16x32_fp8_fp8(av, bpb, obacc[dt], 0, 0, 0);
    }
    __syncthreads();
  }

  la  += __shfl_xor(la, 16);  la  += __shfl_xor(la, 32);
  lbv += __shfl_xor(lbv, 16); lbv += __shfl_xor(lbv, 32);

  u16* obp = outp + ((size_t)(seg * NB + n) * HW) * DH;
  #pragma unroll
  for (int dt = 0; dt < 8; ++dt){
    b16x4 pka = { (short)f2b(oa[dt][0]), (short)f2b(oa[dt][1]),
                  (short)f2b(oa[dt][2]), (short)f2b(oa[dt][3]) };
    b16x4 pkb = { (short)f2b(obacc[dt][0]), (short)f2b(obacc[dt][1]),
                  (short)f2b(obacc[dt][2]), (short)f2b(obacc[dt][3]) };
    *(b16x4*)&obp[(size_t)ja * DH + dt * 16 + quad * 4] = pka;
    *(b16x4*)&obp[(size_t)jb * DH + dt * 16 + quad * 4] = pkb;
  }
  if (quad == 0){
    lsum[(size_t)(seg * NB + n) * HW + ja] = la;
    lsum[(size_t)(seg * NB + n) * HW + jb] = lbv;
  }
}

// ---------------------------------------------------------------------------
// Kernel B2: pval_t[n][j][d] = (sum_s o_s) / (sum_s l_s)
// ---------------------------------------------------------------------------
__global__ __launch_bounds__(256)
void combine(const u16* __restrict__ ob, const float* __restrict__ lb,
             u16* __restrict__ pval_t){
  size_t flat = (size_t)blockIdx.x * 256 + threadIdx.x;
  int d = (int)(flat & 127);
  size_t nj = flat >> 7;
  int j = (int)(nj % HW);
  int n = (int)(nj / HW);
  float acc = 0.f, ls = 0.f;
  #pragma unroll
  for (int s = 0; s < NSPLIT; ++s){
    acc += b2f(ob[((size_t)(s * NB + n) * HW + j) * DH + d]);
    ls  += lb[(size_t)(s * NB + n) * HW + j];
  }
  pval_t[flat] = f2b(acc / ls);
}

// ---------------------------------------------------------------------------
// Kernel C: LDS-staged MFMA implicit-GEMM 3x3 conv + LeakyReLU [+ residual].
// Block = 32d x 64p (one image row y); stages rows {y-DIL, y, y+DIL} (52 KB).
// Weights in A-fragment stream layout (coalesced 16B/lane loads from L2).
// Wave = 32d x 16p: 72 MFMA, 36 LDS B-reads, 72 coalesced A-loads.
// grid (48, 4, NB) block 256, 3 blocks/CU (LDS 3x52.2KB = 156.7 <= 160KB).
// RESM: 0 none, 1 fp32 [c][p], 2 bf16 [p][c].  OUTM: 0 bf16 [p][c], 1 fp32 [c][p].
// ---------------------------------------------------------------------------
template<int DIL, int RESM, int OUTM>
__global__ __launch_bounds__(256, 3)
void mconv(const u16* __restrict__ in_t, const u16* __restrict__ wtf,
           const void* __restrict__ res, void* __restrict__ out){
  __shared__ u16 Xs[3 * 64 * XROW];   // 52224 B

  const int tid  = threadIdx.x;
  const int w    = tid >> 6;
  const int lane = tid & 63;
  const int quad = lane >> 4;
  const int l15  = lane & 15;
  const int n    = blockIdx.z;
  const int y    = blockIdx.x;        // image row
  const int by   = blockIdx.y;        // d-block: d0 = by*32, dtiles by*2, by*2+1
  const int xw   = w * 16;            // wave's x-base within the row

  // stage 3 y-rows (y-DIL, y, y+DIL); OOB rows -> zeros
  const bf16x8 bz8 = {0,0,0,0,0,0,0,0};
  #pragma unroll
  for (int yi = 0; yi < 3; ++yi){
    int ysrc = y + (yi - 1) * DIL;
    bool ok = (unsigned)ysrc < (unsigned)HH;
    #pragma unroll
    for (int pass = 0; pass < 4; ++pass){
      int ch = pass * 256 + tid;      // 0..1023 16B-chunks
      int x  = ch >> 4;
      int g  = ch & 15;
      bf16x8 v = bz8;
      if (ok)
        v = *(const bf16x8*)&in_t[((size_t)n * HW + ysrc * WW + x) * DH + g * 8];
      *(bf16x8*)&Xs[(yi * 64 + x) * XROW + g * 8] = v;
    }
  }
  __syncthreads();

  f32x4 acc[2];
  acc[0] = (f32x4){0.f, 0.f, 0.f, 0.f};
  acc[1] = (f32x4){0.f, 0.f, 0.f, 0.f};

  #pragma unroll
  for (int tap = 0; tap < 9; ++tap){
    const int yi = tap / 3;
    const int dx = (tap % 3 - 1) * DIL;
    const int xp = xw + l15 + dx;
    const bool vx = (unsigned)xp < (unsigned)WW;
    const int xc = vx ? xp : 0;
    const u16* xrow = &Xs[(yi * 64 + xc) * XROW];
    #pragma unroll
    for (int cst = 0; cst < 4; ++cst){
      bf16x8 bf = bz8;
      if (vx) bf = *(const bf16x8*)&xrow[cst * 32 + quad * 8];
      #pragma unroll
      for (int dt = 0; dt < 2; ++dt){
        int fid = (tap * 4 + cst) * 8 + by * 2 + dt;
        bf16x8 af = *(const bf16x8*)&wtf[(size_t)fid * 512 + lane * 8];
        acc[dt] = __builtin_amdgcn_mfma_f32_16x16x32_bf16(af, bf, acc[dt], 0, 0, 0);
      }
    }
  }

  // epilogue: D[row = d-in-tile = quad*4+r][col = p-in-tile = l15]
  const int p = y * WW + xw + l15;
  #pragma unroll
  for (int dt = 0; dt < 2; ++dt){
    const int d0q = by * 32 + dt * 16 + quad * 4;
    float v4[4];
    #pragma unroll
    for (int r = 0; r < 4; ++r){
      float vv = acc[dt][r];
      vv = (vv >= 0.f) ? vv : 0.2f * vv;
      if (RESM == 1)
        vv += ((const float*)res)[((size_t)n * DH + d0q + r) * HW + p];
      v4[r] = vv;
    }
    if (RESM == 2){
      b16x4 rv = *(const b16x4*)&((const u16*)res)[((size_t)n * HW + p) * DH + d0q];
      #pragma unroll
      for (int r = 0; r < 4; ++r) v4[r] += b2f((u16)rv[r]);
    }
    if (OUTM == 0){
      b16x4 pk = { (short)f2b(v4[0]), (short)f2b(v4[1]),
                   (short)f2b(v4[2]), (short)f2b(v4[3]) };
      *(b16x4*)&((u16*)out)[((size_t)n * HW + p) * DH + d0q] = pk;
    } else {
      #pragma unroll
      for (int r = 0; r < 4; ++r)
        ((float*)out)[((size_t)n * DH + d0q + r) * HW + p] = v4[r];
    }
  }
}

// ---------------------------------------------------------------------------
extern "C" void kernel_launch(void* const* d_in, const int* in_sizes, int n_in,
                              void* d_out, int out_size, void* d_ws, size_t ws_size,
                              hipStream_t stream){
  const float* k    = (const float*)d_in[0];
  const float* q    = (const float*)d_in[1];
  const float* v    = (const float*)d_in[2];
  const float* wv   = (const float*)d_in[3];
  const float* wout = (const float*)d_in[4];
  const float* wff1 = (const float*)d_in[5];
  const float* wff2 = (const float*)d_in[6];
  float* out = (float*)d_out;

  const size_t TEN  = (size_t)NB * DH * HW;    // 1,572,864
  const size_t KTEN = (size_t)NB * CKQ * HW;   // 4,718,592
  const size_t WT   = (size_t)9 * DH * DH;     // 147,456
  u8*  kt8    = (u8*)d_ws;
  u8*  qt8    = kt8 + KTEN;
  u8*  val8   = qt8 + KTEN;
  u16* wt1    = (u16*)(val8 + TEN);
  u16* wt2    = wt1 + WT;
  u16* wt3    = wt2 + WT;
  u16* pval_t = wt3 + WT;
  u16* v2_t   = pval_t + TEN;
  u16* tmid_t = v2_t + TEN;
  u16* ob     = tmid_t + TEN;                  // NSPLIT*TEN bf16
  float* lb   = (float*)(ob + (size_t)NSPLIT * TEN);

  tcast8    <<<dim3(48, 2 * NB), 256, 0, stream>>>(k, q, kt8, qt8);
  wprep3    <<<dim3(72, 3), 256, 0, stream>>>(wout, wff1, wff2, wt1, wt2, wt3);
  val_embed8<<<dim3(12, 32, NB), 256, 0, stream>>>(v, wv, val8);
  attn8     <<<dim3(HW / BQ, NSPLIT, NB), 256, 0, stream>>>(kt8, qt8, val8, ob, lb);
  combine   <<<dim3((unsigned)(TEN / 256)), 256, 0, stream>>>(ob, lb, pval_t);
  mconv<1, 1, 0><<<dim3(48, 4, NB), 256, 0, stream>>>(pval_t, wt1, (const void*)v,    (void*)v2_t);
  mconv<2, 0, 0><<<dim3(48, 4, NB), 256, 0, stream>>>(v2_t,   wt2, (const void*)nullptr, (void*)tmid_t);
  mconv<1, 2, 1><<<dim3(48, 4, NB), 256, 0, stream>>>(tmid_t, wt3, (const void*)v2_t, (void*)out);
}